// Round 7
// baseline (7991.233 us; speedup 1.0000x reference)
//
#include <hip/hip_runtime.h>

#define B_ 64
#define S_ 1024
#define I_ 512
#define H_ 512
#define SH_ (S_ * H_)
#define OUT_H (B_ * SH_)
#define BH_ (B_ * H_)

// ---------------------------------------------------------------------------
// Kernel 1: x_proj GEMM.  out[m,n] = sum_k A[m,k]*W[n,k] + bih[n] + bhh[n]
// (unchanged)
// ---------------------------------------------------------------------------
__global__ __launch_bounds__(256) void xproj_kernel(
    const float* __restrict__ A, const float* __restrict__ W,
    const float* __restrict__ bih, const float* __restrict__ bhh,
    float* __restrict__ out)
{
  __shared__ float As[16][132];
  __shared__ float Bs[16][132];
  const int tid = threadIdx.x;
  const int m0 = blockIdx.x * 128;
  const int n0 = blockIdx.y * 128;

  float acc[8][8];
  #pragma unroll
  for (int i = 0; i < 8; ++i)
    #pragma unroll
    for (int j = 0; j < 8; ++j) acc[i][j] = 0.f;

  const int mb = (tid >> 4) * 8;
  const int nb = (tid & 15) * 8;

  for (int kb = 0; kb < I_ / 16; ++kb) {
    const int k0 = kb * 16;
    __syncthreads();
    #pragma unroll
    for (int l = 0; l < 2; ++l) {
      int s  = tid + l * 256;
      int ml = s >> 2;
      int kc = s & 3;
      float4 av = *(const float4*)(A + (size_t)(m0 + ml) * I_ + k0 + kc * 4);
      As[kc*4+0][ml] = av.x; As[kc*4+1][ml] = av.y;
      As[kc*4+2][ml] = av.z; As[kc*4+3][ml] = av.w;
      float4 bv = *(const float4*)(W + (size_t)(n0 + ml) * I_ + k0 + kc * 4);
      Bs[kc*4+0][ml] = bv.x; Bs[kc*4+1][ml] = bv.y;
      Bs[kc*4+2][ml] = bv.z; Bs[kc*4+3][ml] = bv.w;
    }
    __syncthreads();
    #pragma unroll
    for (int k = 0; k < 16; ++k) {
      float4 a0 = *(const float4*)&As[k][mb];
      float4 a1 = *(const float4*)&As[k][mb + 4];
      float4 b0 = *(const float4*)&Bs[k][nb];
      float4 b1 = *(const float4*)&Bs[k][nb + 4];
      float a[8] = {a0.x,a0.y,a0.z,a0.w,a1.x,a1.y,a1.z,a1.w};
      float b[8] = {b0.x,b0.y,b0.z,b0.w,b1.x,b1.y,b1.z,b1.w};
      #pragma unroll
      for (int i = 0; i < 8; ++i)
        #pragma unroll
        for (int j = 0; j < 8; ++j) acc[i][j] += a[i] * b[j];
    }
  }

  float bias[8];
  #pragma unroll
  for (int j = 0; j < 8; ++j) bias[j] = bih[n0 + nb + j] + bhh[n0 + nb + j];
  #pragma unroll
  for (int i = 0; i < 8; ++i) {
    float4 v0 = make_float4(acc[i][0]+bias[0], acc[i][1]+bias[1],
                            acc[i][2]+bias[2], acc[i][3]+bias[3]);
    float4 v1 = make_float4(acc[i][4]+bias[4], acc[i][5]+bias[5],
                            acc[i][6]+bias[6], acc[i][7]+bias[7]);
    float* o = out + (size_t)(m0 + mb + i) * H_ + n0 + nb;
    *(float4*)o       = v0;
    *(float4*)(o + 4) = v1;
  }
}

// ---------------------------------------------------------------------------
// Kernel 2: init — zero tag-slot 0.  (d_ws re-poisoned to 0xAA per launch.)
// Slot0's first tagged write (h_2) carries tag 1; poison bit31=1 would alias
// it, so slot0 must be cleared.  Slot1's poison (bit31=1) differs from the
// expected tag 0 at t=1, so it needs no init.  h0 read from d_in at t=0.
// ---------------------------------------------------------------------------
__global__ __launch_bounds__(256) void init_kernel(unsigned* __restrict__ hbu)
{
  int i = blockIdx.x * 256 + threadIdx.x;
  if (i < BH_) hbu[i] = 0u;
}

// ---------------------------------------------------------------------------
// DPP full-wave reduction (VALU pipe, no LDS, no shuffle).
// rowsum16 (0xB1,0x4E,0x141,0x140) is HW-proven numerically (R7 bench run
// passed with it).  Then row_bcast15 (0x142: lane15->16..31, lane47->48..63)
// and row_bcast31 (0x143: lane31->32..63) complete the 64-lane sum:
//   after rowsum16:  row r lanes hold S_r
//   after bcast15+:  row1 = S1+S0, row3 = S3+S2
//   after bcast31+:  rows2,3 += (S1+S0)  ->  lanes 48..63 = S0+S1+S2+S3.
// bound_ctrl=true makes out-of-pattern source lanes contribute 0.
// ---------------------------------------------------------------------------
template <int CTRL>
__device__ __forceinline__ float dpp_add(float x) {
  return x + __int_as_float(__builtin_amdgcn_update_dpp(
      0, __float_as_int(x), CTRL, 0xF, 0xF, true));
}
__device__ __forceinline__ float wavesum64(float x) {
  x = dpp_add<0xB1>(x);    // quad_perm [1,0,3,2]  : xor1
  x = dpp_add<0x4E>(x);    // quad_perm [2,3,0,1]  : xor2
  x = dpp_add<0x141>(x);   // row_half_mirror      : xor4-equiv
  x = dpp_add<0x140>(x);   // row_mirror           : xor8-equiv
  x = dpp_add<0x142>(x);   // row_bcast15
  x = dpp_add<0x143>(x);   // row_bcast31
  return x;                // lanes 48..63 hold the full 64-lane sum
}

#define FMA4(A, W4, s) \
  A.x += W4.x * (s); A.y += W4.y * (s); A.z += W4.z * (s); A.w += W4.w * (s)

// W panel: k-chunk J column (64J + lane) for the 8 output rows, as 2 float4.
#define LDW(J) \
  float4 W##J##A = make_float4(q0[64*J], q1[64*J], q2[64*J], q3[64*J]); \
  float4 W##J##B = make_float4(q4[64*J], q5[64*J], q6[64*J], q7[64*J]);

#define FMAJ(J, HV) \
  FMA4(aA, W##J##A, HV); FMA4(aB, W##J##B, HV);

#define AL(P) __hip_atomic_load((P), __ATOMIC_RELAXED, __HIP_MEMORY_SCOPE_AGENT)

// ---------------------------------------------------------------------------
// Kernel 3: recurrence — R11: wave-autonomous at the PROVEN W size.
// R10 post-mortem: 128 W floats/lane is ALWAYS rematerialized (VGPR 92,
// FETCH +87MB, 3200us).  64 floats/lane is the proven-resident size (R8/R9,
// VGPR 88).  So shrink the wave's tile, not the autonomy:
//   * 4096 waves = 256 WGs x 1024 thr (16 waves/CU, waves_per_eu(4,4)
//     -> hard 128-VGPR cap, no silent remat/spill ambiguity);
//   * wave = (batch b, 8-output slice): W = 8 rows x K=512 = 64 floats/lane
//     in 16 named float4;  lane L spin-loads h[b][64j+L] (8 tagged dwords,
//     coalesced), FMA straight from spin registers — NO LDS anywhere;
//   * k-reduce fully in-wave: wavesum64 DPP x8 (no barrier, no LDS RTT,
//     no cross-wave fan-in); lanes 48..55 select acc[lane&7] (7 cndmask)
//     and finalize+publish EVERY step;
//   * xp prefetched one step ahead (hidden under spin+FMA).
// Locality: WG g -> XCD slot x=g&7; wave w serves batch 8x+(w&7), slice
// s = (g>>3)*2 + (w>>3) (outputs [8s,8s+8)).  Batch b's 64 waves all sit
// in XCD slot b>>3; each WG mixes 8 batches -> decorrelated stalls.
// Safety (unchanged induction; publish is data-dependent on ALL h_{t-1}
// loads returning, so slot overwrite can't outrun any reader).  Tag
// protocol, init, ternary ReLU + bit31 mask: byte-identical to R4..R9.
// ---------------------------------------------------------------------------
__global__ __launch_bounds__(1024)
__attribute__((amdgpu_waves_per_eu(4, 4)))
void recur_kernel(
    const float* __restrict__ Whh, const float* __restrict__ h0,
    float* __restrict__ out, unsigned* __restrict__ hbu)
{
  const int tid  = threadIdx.x;
  const int lane = tid & 63;
  const int w    = tid >> 6;            // wave id 0..15
  const int g    = blockIdx.x;
  const int x    = g & 7;               // XCD slot
  const int b    = x * 8 + (w & 7);     // batch 0..63
  const int s    = (g >> 3) * 2 + (w >> 3);  // output slice 0..63
  const int os   = s * 8;               // outputs [os, os+8)

  // ---- W panel: rows os..os+7, cols {64j+lane} -> 16 named float4 ----
  const float* q0 = Whh + (size_t)(os + 0) * H_ + lane;
  const float* q1 = Whh + (size_t)(os + 1) * H_ + lane;
  const float* q2 = Whh + (size_t)(os + 2) * H_ + lane;
  const float* q3 = Whh + (size_t)(os + 3) * H_ + lane;
  const float* q4 = Whh + (size_t)(os + 4) * H_ + lane;
  const float* q5 = Whh + (size_t)(os + 5) * H_ + lane;
  const float* q6 = Whh + (size_t)(os + 6) * H_ + lane;
  const float* q7 = Whh + (size_t)(os + 7) * H_ + lane;
  LDW(0) LDW(1) LDW(2) LDW(3) LDW(4) LDW(5) LDW(6) LDW(7)

  // finalists: lanes 48..55, output fo = os + (lane&7) of batch b
  const bool fin = (lane >= 48) && (lane < 56);
  const int  fo  = os + (lane & 7);
  float* outp    = out + (size_t)b * SH_ + fo;     // advances by H_ / step
  unsigned* hdb  = hbu + (size_t)b * H_ + fo;      // + slot*BH_

  float xpn = 0.f;
  if (fin) xpn = *outp;                 // xp(t=0) prologue prefetch

  for (int t = 0; t < S_; ++t) {
    const float xp = xpn;

    // ---- spin-load this lane's 8 h values (tagged, coalesced) ----
    float hv0, hv1, hv2, hv3, hv4, hv5, hv6, hv7;
    if (t == 0) {
      const float* hp = h0 + (size_t)b * H_ + lane;
      hv0 = hp[0];   hv1 = hp[64];  hv2 = hp[128]; hv3 = hp[192];
      hv4 = hp[256]; hv5 = hp[320]; hv6 = hp[384]; hv7 = hp[448];
    } else {
      const unsigned* hs = hbu + (t & 1) * BH_ + (size_t)b * H_ + lane;
      const unsigned expct = ((unsigned)t >> 1) & 1u;
      unsigned u0 = AL(hs +   0), u1 = AL(hs +  64);
      unsigned u2 = AL(hs + 128), u3 = AL(hs + 192);
      unsigned u4 = AL(hs + 256), u5 = AL(hs + 320);
      unsigned u6 = AL(hs + 384), u7 = AL(hs + 448);
      while ((u0 >> 31) != expct) u0 = AL(hs +   0);
      while ((u1 >> 31) != expct) u1 = AL(hs +  64);
      while ((u2 >> 31) != expct) u2 = AL(hs + 128);
      while ((u3 >> 31) != expct) u3 = AL(hs + 192);
      while ((u4 >> 31) != expct) u4 = AL(hs + 256);
      while ((u5 >> 31) != expct) u5 = AL(hs + 320);
      while ((u6 >> 31) != expct) u6 = AL(hs + 384);
      while ((u7 >> 31) != expct) u7 = AL(hs + 448);
      hv0 = __uint_as_float(u0 & 0x7fffffffu);
      hv1 = __uint_as_float(u1 & 0x7fffffffu);
      hv2 = __uint_as_float(u2 & 0x7fffffffu);
      hv3 = __uint_as_float(u3 & 0x7fffffffu);
      hv4 = __uint_as_float(u4 & 0x7fffffffu);
      hv5 = __uint_as_float(u5 & 0x7fffffffu);
      hv6 = __uint_as_float(u6 & 0x7fffffffu);
      hv7 = __uint_as_float(u7 & 0x7fffffffu);
    }

    // ---- 64 FMA/lane: 8 outputs x 8 k, straight from spin regs ----
    float4 aA = make_float4(0.f, 0.f, 0.f, 0.f);
    float4 aB = make_float4(0.f, 0.f, 0.f, 0.f);
    FMAJ(0, hv0) FMAJ(1, hv1) FMAJ(2, hv2) FMAJ(3, hv3)
    FMAJ(4, hv4) FMAJ(5, hv5) FMAJ(6, hv6) FMAJ(7, hv7)

    // ---- full 64-lane k-reduce, pure DPP (lanes 48..63 hold totals) ----
    aA.x = wavesum64(aA.x); aA.y = wavesum64(aA.y);
    aA.z = wavesum64(aA.z); aA.w = wavesum64(aA.w);
    aB.x = wavesum64(aB.x); aB.y = wavesum64(aB.y);
    aB.z = wavesum64(aB.z); aB.w = wavesum64(aB.w);

    // ---- finalize: lanes 48..55, output os+(lane&7), EVERY step ----
    if (fin) {
      const int li = lane & 7;
      float4 s4 = (li & 4) ? aB : aA;
      float t0  = (li & 2) ? s4.z : s4.x;
      float t1  = (li & 2) ? s4.w : s4.y;
      float sel = (li & 1) ? t1 : t0;
      float pre = xp + sel;
      float v = pre > 0.f ? pre : 0.f;          // ternary: never -0.0
      const unsigned tg = ((((unsigned)(t + 1)) >> 1) & 1u) << 31;
      __hip_atomic_store(hdb + ((t + 1) & 1) * BH_,
                         (__float_as_uint(v) & 0x7fffffffu) | tg,
                         __ATOMIC_RELAXED, __HIP_MEMORY_SCOPE_AGENT);
      *outp = v;                                 // out[b,t,:] = h_{t+1}
      if (t == S_ - 1)
        out[(size_t)OUT_H + (size_t)b * H_ + fo] = v;   // h_final
      outp += H_;
      if (t + 1 < S_) xpn = *outp;   // prefetch next step's xp
    }
    // No barriers, no LDS: peers couple only through the tagged h slots;
    // the spin is the synchronization point.
  }
}

// ---------------------------------------------------------------------------
extern "C" void kernel_launch(void* const* d_in, const int* in_sizes, int n_in,
                              void* d_out, int out_size, void* d_ws, size_t ws_size,
                              hipStream_t stream)
{
  const float* inputs = (const float*)d_in[0];  // [B,S,I]
  const float* h0     = (const float*)d_in[1];  // [1,B,H]
  const float* w_ih   = (const float*)d_in[2];  // [H,I]
  const float* w_hh   = (const float*)d_in[3];  // [H,H]
  const float* b_ih   = (const float*)d_in[4];  // [H]
  const float* b_hh   = (const float*)d_in[5];  // [H]
  float* out = (float*)d_out;                   // [B,S,H] ++ [1,B,H] h_final

  unsigned* hbu = (unsigned*)d_ws;              // 2 tagged h slots

  dim3 g1(512, 4);
  xproj_kernel<<<g1, 256, 0, stream>>>(inputs, w_ih, b_ih, b_hh, out);
  init_kernel<<<128, 256, 0, stream>>>(hbu);
  recur_kernel<<<256, 1024, 0, stream>>>(w_hh, h0, out, hbu);
}

// Round 8
// 6569.953 us; speedup vs baseline: 1.2163x; 1.2163x over previous
//
#include <hip/hip_runtime.h>

#define B_ 64
#define S_ 1024
#define I_ 512
#define H_ 512
#define SH_ (S_ * H_)
#define OUT_H (B_ * SH_)
#define BH_ (B_ * H_)

// ---------------------------------------------------------------------------
// Kernel 1: x_proj GEMM.  out[m,n] = sum_k A[m,k]*W[n,k] + bih[n] + bhh[n]
// (unchanged)
// ---------------------------------------------------------------------------
__global__ __launch_bounds__(256) void xproj_kernel(
    const float* __restrict__ A, const float* __restrict__ W,
    const float* __restrict__ bih, const float* __restrict__ bhh,
    float* __restrict__ out)
{
  __shared__ float As[16][132];
  __shared__ float Bs[16][132];
  const int tid = threadIdx.x;
  const int m0 = blockIdx.x * 128;
  const int n0 = blockIdx.y * 128;

  float acc[8][8];
  #pragma unroll
  for (int i = 0; i < 8; ++i)
    #pragma unroll
    for (int j = 0; j < 8; ++j) acc[i][j] = 0.f;

  const int mb = (tid >> 4) * 8;
  const int nb = (tid & 15) * 8;

  for (int kb = 0; kb < I_ / 16; ++kb) {
    const int k0 = kb * 16;
    __syncthreads();
    #pragma unroll
    for (int l = 0; l < 2; ++l) {
      int s  = tid + l * 256;
      int ml = s >> 2;
      int kc = s & 3;
      float4 av = *(const float4*)(A + (size_t)(m0 + ml) * I_ + k0 + kc * 4);
      As[kc*4+0][ml] = av.x; As[kc*4+1][ml] = av.y;
      As[kc*4+2][ml] = av.z; As[kc*4+3][ml] = av.w;
      float4 bv = *(const float4*)(W + (size_t)(n0 + ml) * I_ + k0 + kc * 4);
      Bs[kc*4+0][ml] = bv.x; Bs[kc*4+1][ml] = bv.y;
      Bs[kc*4+2][ml] = bv.z; Bs[kc*4+3][ml] = bv.w;
    }
    __syncthreads();
    #pragma unroll
    for (int k = 0; k < 16; ++k) {
      float4 a0 = *(const float4*)&As[k][mb];
      float4 a1 = *(const float4*)&As[k][mb + 4];
      float4 b0 = *(const float4*)&Bs[k][nb];
      float4 b1 = *(const float4*)&Bs[k][nb + 4];
      float a[8] = {a0.x,a0.y,a0.z,a0.w,a1.x,a1.y,a1.z,a1.w};
      float b[8] = {b0.x,b0.y,b0.z,b0.w,b1.x,b1.y,b1.z,b1.w};
      #pragma unroll
      for (int i = 0; i < 8; ++i)
        #pragma unroll
        for (int j = 0; j < 8; ++j) acc[i][j] += a[i] * b[j];
    }
  }

  float bias[8];
  #pragma unroll
  for (int j = 0; j < 8; ++j) bias[j] = bih[n0 + nb + j] + bhh[n0 + nb + j];
  #pragma unroll
  for (int i = 0; i < 8; ++i) {
    float4 v0 = make_float4(acc[i][0]+bias[0], acc[i][1]+bias[1],
                            acc[i][2]+bias[2], acc[i][3]+bias[3]);
    float4 v1 = make_float4(acc[i][4]+bias[4], acc[i][5]+bias[5],
                            acc[i][6]+bias[6], acc[i][7]+bias[7]);
    float* o = out + (size_t)(m0 + mb + i) * H_ + n0 + nb;
    *(float4*)o       = v0;
    *(float4*)(o + 4) = v1;
  }
}

// ---------------------------------------------------------------------------
// Kernel 2: init — zero tag-slot 0.  (d_ws re-poisoned to 0xAA per launch.)
// Slot0's first tagged write (h_2) carries tag 1; poison bit31=1 would alias
// it, so slot0 must be cleared.  Slot1's poison (bit31=1) differs from the
// expected tag 0 at t=1, so it needs no init.  h0 read from d_in at t=0.
// ---------------------------------------------------------------------------
__global__ __launch_bounds__(256) void init_kernel(unsigned* __restrict__ hbu)
{
  int i = blockIdx.x * 256 + threadIdx.x;
  if (i < BH_) hbu[i] = 0u;
}

// ---------------------------------------------------------------------------
// DPP full-wave reduction (VALU pipe, no LDS, no shuffle).
// rowsum16 part (0xB1,0x4E,0x141,0x140) HW-proven (R7 run); bcast15+bcast31
// complete the 64-lane sum; HW-proven in the R11 run (passed).
// bound_ctrl=true: out-of-pattern source lanes contribute 0.
// ---------------------------------------------------------------------------
template <int CTRL>
__device__ __forceinline__ float dpp_add(float x) {
  return x + __int_as_float(__builtin_amdgcn_update_dpp(
      0, __float_as_int(x), CTRL, 0xF, 0xF, true));
}
__device__ __forceinline__ float wavesum64(float x) {
  x = dpp_add<0xB1>(x);    // quad_perm [1,0,3,2]  : xor1
  x = dpp_add<0x4E>(x);    // quad_perm [2,3,0,1]  : xor2
  x = dpp_add<0x141>(x);   // row_half_mirror      : xor4-equiv
  x = dpp_add<0x140>(x);   // row_mirror           : xor8-equiv
  x = dpp_add<0x142>(x);   // row_bcast15
  x = dpp_add<0x143>(x);   // row_bcast31
  return x;                // lanes 48..63 hold the full 64-lane sum
}

#define FMA4(A, W4, s) \
  A.x += W4.x * (s); A.y += W4.y * (s); A.z += W4.z * (s); A.w += W4.w * (s)

// W panel: k-chunk J column (64J + lane) for the 8 output rows, as 2 float4,
// then PINNED: an empty asm with "+v" makes each value asm-defined ->
// NOT rematerializable, NOT sinkable.  This is the R11 fix: R8/R9 kept W
// resident only because their transpose-shuffle blocked remat; R10/R11's
// bare scalar gathers were legally re-loaded from L2/L3 every step
// (VGPR 52, FETCH +320MB).  The pin forces true residency.
#define LDW(J) \
  float4 W##J##A = make_float4(q0[64*J], q1[64*J], q2[64*J], q3[64*J]); \
  float4 W##J##B = make_float4(q4[64*J], q5[64*J], q6[64*J], q7[64*J]); \
  asm volatile("" : "+v"(W##J##A.x), "+v"(W##J##A.y), "+v"(W##J##A.z), \
                    "+v"(W##J##A.w), "+v"(W##J##B.x), "+v"(W##J##B.y), \
                    "+v"(W##J##B.z), "+v"(W##J##B.w));

#define FMAJ(J, HV) \
  FMA4(aA, W##J##A, HV); FMA4(aB, W##J##B, HV);

#define AL(P) __hip_atomic_load((P), __ATOMIC_RELAXED, __HIP_MEMORY_SCOPE_AGENT)

// ---------------------------------------------------------------------------
// Kernel 3: recurrence — R12: R11's wave-autonomous structure (which PASSED
// and is protocol-proven) + the remat fix.
//   * 4096 waves = 256 WGs x 1024 thr (16 waves/CU, waves_per_eu(4,4) ->
//     128-VGPR cap); wave = (batch b, 8 outputs) with FULL K=512;
//   * W = 64 floats/lane in 16 float4, ASM-PINNED (see LDW) -> resident;
//   * lane L spin-loads h[b][64j+L], j=0..7: ONE combined poll loop (all 8
//     loads issued in parallel each iteration -> detect lag = 1 RTT after
//     the last producer store, vs up to 8 chained RTTs in R11);
//   * FMA straight from spin regs; k-reduce pure DPP (wavesum64 x8);
//     lanes 48..55 finalize + tagged-publish EVERY step; no LDS, no
//     barriers anywhere in the t-loop;
//   * xp prefetched one step ahead (hidden under spin+FMA).
// Locality: WG g -> XCD slot g&7; batch b = 8*(g&7)+(w&7) -> all 64 waves
// of batch b on one XCD; each WG mixes 8 batches (decorrelated stalls).
// Safety: identical induction to R4..R11 (publish of h_{t+1} is
// data-dependent on ALL of h_t being detected).  Tag protocol, init,
// ternary ReLU + bit31 mask: byte-identical.
// ---------------------------------------------------------------------------
__global__ __launch_bounds__(1024)
__attribute__((amdgpu_waves_per_eu(4, 4)))
void recur_kernel(
    const float* __restrict__ Whh, const float* __restrict__ h0,
    float* __restrict__ out, unsigned* __restrict__ hbu)
{
  const int tid  = threadIdx.x;
  const int lane = tid & 63;
  const int w    = tid >> 6;            // wave id 0..15
  const int g    = blockIdx.x;
  const int x    = g & 7;               // XCD slot
  const int b    = x * 8 + (w & 7);     // batch 0..63
  const int s    = (g >> 3) * 2 + (w >> 3);  // output slice 0..63
  const int os   = s * 8;               // outputs [os, os+8)

  // ---- W panel: rows os..os+7, cols {64j+lane} -> 16 pinned float4 ----
  const float* q0 = Whh + (size_t)(os + 0) * H_ + lane;
  const float* q1 = Whh + (size_t)(os + 1) * H_ + lane;
  const float* q2 = Whh + (size_t)(os + 2) * H_ + lane;
  const float* q3 = Whh + (size_t)(os + 3) * H_ + lane;
  const float* q4 = Whh + (size_t)(os + 4) * H_ + lane;
  const float* q5 = Whh + (size_t)(os + 5) * H_ + lane;
  const float* q6 = Whh + (size_t)(os + 6) * H_ + lane;
  const float* q7 = Whh + (size_t)(os + 7) * H_ + lane;
  LDW(0) LDW(1) LDW(2) LDW(3) LDW(4) LDW(5) LDW(6) LDW(7)

  // finalists: lanes 48..55, output fo = os + (lane&7) of batch b
  const bool fin = (lane >= 48) && (lane < 56);
  const int  fo  = os + (lane & 7);
  float* outp    = out + (size_t)b * SH_ + fo;     // advances by H_ / step
  unsigned* hdb  = hbu + (size_t)b * H_ + fo;      // + slot*BH_

  float xpn = 0.f;
  if (fin) xpn = *outp;                 // xp(t=0) prologue prefetch

  for (int t = 0; t < S_; ++t) {
    const float xp = xpn;

    // ---- spin-load this lane's 8 h values: ONE combined poll loop ----
    float hv0, hv1, hv2, hv3, hv4, hv5, hv6, hv7;
    if (t == 0) {
      const float* hp = h0 + (size_t)b * H_ + lane;
      hv0 = hp[0];   hv1 = hp[64];  hv2 = hp[128]; hv3 = hp[192];
      hv4 = hp[256]; hv5 = hp[320]; hv6 = hp[384]; hv7 = hp[448];
    } else {
      const unsigned* hs = hbu + (t & 1) * BH_ + (size_t)b * H_ + lane;
      const unsigned e = ((unsigned)t >> 1) & 1u;
      unsigned u0, u1, u2, u3, u4, u5, u6, u7;
      for (;;) {
        u0 = AL(hs +   0); u1 = AL(hs +  64);
        u2 = AL(hs + 128); u3 = AL(hs + 192);
        u4 = AL(hs + 256); u5 = AL(hs + 320);
        u6 = AL(hs + 384); u7 = AL(hs + 448);
        unsigned bad = ((u0 >> 31) ^ e) | ((u1 >> 31) ^ e)
                     | ((u2 >> 31) ^ e) | ((u3 >> 31) ^ e)
                     | ((u4 >> 31) ^ e) | ((u5 >> 31) ^ e)
                     | ((u6 >> 31) ^ e) | ((u7 >> 31) ^ e);
        if (!bad) break;
      }
      hv0 = __uint_as_float(u0 & 0x7fffffffu);
      hv1 = __uint_as_float(u1 & 0x7fffffffu);
      hv2 = __uint_as_float(u2 & 0x7fffffffu);
      hv3 = __uint_as_float(u3 & 0x7fffffffu);
      hv4 = __uint_as_float(u4 & 0x7fffffffu);
      hv5 = __uint_as_float(u5 & 0x7fffffffu);
      hv6 = __uint_as_float(u6 & 0x7fffffffu);
      hv7 = __uint_as_float(u7 & 0x7fffffffu);
    }

    // ---- 64 FMA/lane: 8 outputs x 8 k, straight from spin regs ----
    float4 aA = make_float4(0.f, 0.f, 0.f, 0.f);
    float4 aB = make_float4(0.f, 0.f, 0.f, 0.f);
    FMAJ(0, hv0) FMAJ(1, hv1) FMAJ(2, hv2) FMAJ(3, hv3)
    FMAJ(4, hv4) FMAJ(5, hv5) FMAJ(6, hv6) FMAJ(7, hv7)

    // ---- full 64-lane k-reduce, pure DPP (lanes 48..63 hold totals) ----
    aA.x = wavesum64(aA.x); aA.y = wavesum64(aA.y);
    aA.z = wavesum64(aA.z); aA.w = wavesum64(aA.w);
    aB.x = wavesum64(aB.x); aB.y = wavesum64(aB.y);
    aB.z = wavesum64(aB.z); aB.w = wavesum64(aB.w);

    // ---- finalize: lanes 48..55, output os+(lane&7), EVERY step ----
    if (fin) {
      const int li = lane & 7;
      float4 s4 = (li & 4) ? aB : aA;
      float t0  = (li & 2) ? s4.z : s4.x;
      float t1  = (li & 2) ? s4.w : s4.y;
      float sel = (li & 1) ? t1 : t0;
      float pre = xp + sel;
      float v = pre > 0.f ? pre : 0.f;          // ternary: never -0.0
      const unsigned tg = ((((unsigned)(t + 1)) >> 1) & 1u) << 31;
      __hip_atomic_store(hdb + ((t + 1) & 1) * BH_,
                         (__float_as_uint(v) & 0x7fffffffu) | tg,
                         __ATOMIC_RELAXED, __HIP_MEMORY_SCOPE_AGENT);
      *outp = v;                                 // out[b,t,:] = h_{t+1}
      if (t == S_ - 1)
        out[(size_t)OUT_H + (size_t)b * H_ + fo] = v;   // h_final
      outp += H_;
      if (t + 1 < S_) xpn = *outp;   // prefetch next step's xp
    }
    // No barriers, no LDS: peers couple only through the tagged h slots;
    // the spin is the synchronization point.
  }
}

// ---------------------------------------------------------------------------
extern "C" void kernel_launch(void* const* d_in, const int* in_sizes, int n_in,
                              void* d_out, int out_size, void* d_ws, size_t ws_size,
                              hipStream_t stream)
{
  const float* inputs = (const float*)d_in[0];  // [B,S,I]
  const float* h0     = (const float*)d_in[1];  // [1,B,H]
  const float* w_ih   = (const float*)d_in[2];  // [H,I]
  const float* w_hh   = (const float*)d_in[3];  // [H,H]
  const float* b_ih   = (const float*)d_in[4];  // [H]
  const float* b_hh   = (const float*)d_in[5];  // [H]
  float* out = (float*)d_out;                   // [B,S,H] ++ [1,B,H] h_final

  unsigned* hbu = (unsigned*)d_ws;              // 2 tagged h slots

  dim3 g1(512, 4);
  xproj_kernel<<<g1, 256, 0, stream>>>(inputs, w_ih, b_ih, b_hh, out);
  init_kernel<<<128, 256, 0, stream>>>(hbu);
  recur_kernel<<<256, 1024, 0, stream>>>(w_hh, h0, out, hbu);
}